// Round 2
// baseline (380.213 us; speedup 1.0000x reference)
//
#include <hip/hip_runtime.h>
#include <stdint.h>

#define NN 8192
#define DD 1024
#define CCHUNK 16         // column chunks (split-LSE): grid = 64 x 16 = 1024 blocks -> 4/CU
#define BM 128            // rows per block
#define BN 128            // cols per strip
#define BK 32             // K tile
#define L2E 1.4426950408889634f

typedef short s8v __attribute__((ext_vector_type(8)));   // 8 bf16 = 4 VGPR
typedef float f4v __attribute__((ext_vector_type(4)));   // MFMA C/D
typedef unsigned short u16;

__device__ __forceinline__ void async16(const void* g, void* l) {
  __builtin_amdgcn_global_load_lds(
      (const __attribute__((address_space(1))) void*)g,
      (__attribute__((address_space(3))) void*)l, 16, 0, 0);
}

__device__ __forceinline__ u16 f2bf(float f) {
  unsigned u = __float_as_uint(f);
  u += 0x7fffu + ((u >> 16) & 1u);   // RNE
  return (u16)(u >> 16);
}

// ---- fp32 -> bf16 conversion of both operands, fused with exact fp32 diagonal ----
__global__ void cvt_diag(const float* __restrict__ r, const float* __restrict__ l,
                         u16* __restrict__ rb, u16* __restrict__ lb,
                         float* __restrict__ accum) {
  int tid = threadIdx.x, lane = tid & 63, w = tid >> 6;
  size_t i = (size_t)blockIdx.x * blockDim.x + tid;  // float4 index
  float4 a = ((const float4*)r)[i];
  float4 b = ((const float4*)l)[i];
  ushort4 oa, ob;
  oa.x = f2bf(a.x); oa.y = f2bf(a.y); oa.z = f2bf(a.z); oa.w = f2bf(a.w);
  ob.x = f2bf(b.x); ob.y = f2bf(b.y); ob.z = f2bf(b.z); ob.w = f2bf(b.w);
  ((ushort4*)rb)[i] = oa;
  ((ushort4*)lb)[i] = ob;
  // diagonal partial: R and L at identical flat offsets -> same (row, d)
  float s = a.x * b.x + a.y * b.y + a.z * b.z + a.w * b.w;
#pragma unroll
  for (int m = 1; m <= 32; m <<= 1) s += __shfl_xor(s, m);
  __shared__ float red[4];
  if (lane == 0) red[w] = s;
  __syncthreads();
  if (tid == 0) atomicAdd(accum, red[0] + red[1] + red[2] + red[3]);
}

// ---- fused bf16 GEMM + online logsumexp over one column chunk ----
// Online (m,s) kept PER THREAD over each lane's private column subset; the
// cross-lane m-aware merge happens once at kernel end (keeps the DS pipe free
// for ds_read_b128 in the hot loop).
__global__ __launch_bounds__(256, 2) void gemm_lse(
    const u16* __restrict__ Rb, const u16* __restrict__ Lb,
    float* __restrict__ pm, float* __restrict__ ps) {
  __shared__ u16 As[BM * BK];          // 8 KB
  __shared__ u16 Bs[BN * BK];          // 8 KB
  __shared__ float smm[2][BM], sms[2][BM];

  const int tid = threadIdx.x, lane = tid & 63, w = tid >> 6;
  const int wy = w >> 1, wx = w & 1;
  const int quad = lane >> 4, l15 = lane & 15;
  const int row0 = blockIdx.x * BM;
  const int col0 = blockIdx.y * (NN / CCHUNK);

  // staging assignments: granule g = (w*2+c)*64 + lane; row=g>>2, kq=g&3
  size_t gAo[2], gBo[2];
  u16 *lAp[2], *lBp[2];
#pragma unroll
  for (int c = 0; c < 2; ++c) {
    int g = (w * 2 + c) * 64 + lane;
    gAo[c] = (size_t)(row0 + (g >> 2)) * DD + (g & 3) * 8;
    gBo[c] = (size_t)(g >> 2) * DD + (g & 3) * 8;   // + strip col base later
    lAp[c] = As + (w * 2 + c) * 512;
    lBp[c] = Bs + (w * 2 + c) * 512;
  }

  float m_run[4][4], s_run[4][4];
#pragma unroll
  for (int i = 0; i < 4; ++i)
#pragma unroll
    for (int j = 0; j < 4; ++j) { m_run[i][j] = -__builtin_inff(); s_run[i][j] = 0.f; }

  for (int strip = 0; strip < (NN / CCHUNK) / BN; ++strip) {
    const u16* gB_base = Lb + (size_t)(col0 + strip * BN) * DD;
    f4v acc[4][4];
#pragma unroll
    for (int ri = 0; ri < 4; ++ri)
#pragma unroll
      for (int ci = 0; ci < 4; ++ci) acc[ri][ci] = (f4v){0.f, 0.f, 0.f, 0.f};

    for (int kt = 0; kt < DD / BK; ++kt) {
      const int k = kt * BK;
      async16(Rb + gAo[0] + k, lAp[0]);
      async16(Rb + gAo[1] + k, lAp[1]);
      async16(gB_base + gBo[0] + k, lBp[0]);
      async16(gB_base + gBo[1] + k, lBp[1]);
      __syncthreads();
      s8v a[4], b[4];
#pragma unroll
      for (int ri = 0; ri < 4; ++ri)
        a[ri] = *(const s8v*)(As + (wy * 64 + ri * 16 + l15) * BK + quad * 8);
#pragma unroll
      for (int ci = 0; ci < 4; ++ci)
        b[ci] = *(const s8v*)(Bs + (wx * 64 + ci * 16 + l15) * BK + quad * 8);
#pragma unroll
      for (int ri = 0; ri < 4; ++ri)
#pragma unroll
        for (int ci = 0; ci < 4; ++ci)
          acc[ri][ci] = __builtin_amdgcn_mfma_f32_16x16x32_bf16(a[ri], b[ci], acc[ri][ci], 0, 0, 0);
      __syncthreads();
    }

    // per-thread online update, pure VALU (no cross-lane traffic in hot loop)
    // this thread's cols for (ri,reg): {wx*64 + ci*16 + l15 : ci in 0..3} per strip
#pragma unroll
    for (int ri = 0; ri < 4; ++ri) {
#pragma unroll
      for (int reg = 0; reg < 4; ++reg) {
        float v0 = acc[ri][0][reg], v1 = acc[ri][1][reg];
        float v2 = acc[ri][2][reg], v3 = acc[ri][3][reg];
        float t = fmaxf(fmaxf(v0, v1), fmaxf(v2, v3));
        float mo = m_run[ri][reg];
        float mn = fmaxf(mo, t);
        float c = mn * L2E;
        float p = exp2f(fmaf(v0, L2E, -c)) + exp2f(fmaf(v1, L2E, -c)) +
                  exp2f(fmaf(v2, L2E, -c)) + exp2f(fmaf(v3, L2E, -c));
        s_run[ri][reg] = fmaf(s_run[ri][reg], exp2f(fmaf(mo, L2E, -c)), p);
        m_run[ri][reg] = mn;
      }
    }
  }

  // ---- end-of-kernel merge ----
  // 1) m-aware butterfly across the 16 lanes of each quad (same output row)
#pragma unroll
  for (int ri = 0; ri < 4; ++ri) {
#pragma unroll
    for (int reg = 0; reg < 4; ++reg) {
      float m = m_run[ri][reg], s = s_run[ri][reg];
#pragma unroll
      for (int msk = 1; msk <= 8; msk <<= 1) {
        float om = __shfl_xor(m, msk);
        float os = __shfl_xor(s, msk);
        float M = fmaxf(m, om);
        s = s * exp2f((m - M) * L2E) + os * exp2f((om - M) * L2E);
        m = M;
      }
      m_run[ri][reg] = m; s_run[ri][reg] = s;
    }
  }
  // 2) merge the two waves (wx=0/1) that share rows, via LDS
  __syncthreads();
  if (l15 == 0) {
#pragma unroll
    for (int ri = 0; ri < 4; ++ri)
#pragma unroll
      for (int reg = 0; reg < 4; ++reg) {
        int r = wy * 64 + ri * 16 + quad * 4 + reg;
        smm[wx][r] = m_run[ri][reg];
        sms[wx][r] = s_run[ri][reg];
      }
  }
  __syncthreads();
  if (tid < BM) {
    float m1 = smm[0][tid], m2 = smm[1][tid];
    float M = fmaxf(m1, m2);
    float S = sms[0][tid] * exp2f((m1 - M) * L2E) + sms[1][tid] * exp2f((m2 - M) * L2E);
    pm[(size_t)(row0 + tid) * CCHUNK + blockIdx.y] = M;
    ps[(size_t)(row0 + tid) * CCHUNK + blockIdx.y] = S;
  }
}

// ---- combine chunk partials -> lse per row -> sum ----
__global__ void lse_merge(const float* __restrict__ pm, const float* __restrict__ ps,
                          float* __restrict__ accum) {
  int tid = threadIdx.x, lane = tid & 63, w = tid >> 6;
  int row = blockIdx.x * 256 + tid;
  float M = -__builtin_inff();
#pragma unroll
  for (int c = 0; c < CCHUNK; ++c) M = fmaxf(M, pm[(size_t)row * CCHUNK + c]);
  float S = 0.f;
#pragma unroll
  for (int c = 0; c < CCHUNK; ++c)
    S += ps[(size_t)row * CCHUNK + c] * exp2f((pm[(size_t)row * CCHUNK + c] - M) * L2E);
  float lse = M + logf(S);
#pragma unroll
  for (int m = 1; m <= 32; m <<= 1) lse += __shfl_xor(lse, m);
  __shared__ float red[4];
  if (lane == 0) red[w] = lse;
  __syncthreads();
  if (tid == 0) atomicAdd(accum, red[0] + red[1] + red[2] + red[3]);
}

__global__ void finalize(const float* __restrict__ accum, float* __restrict__ out) {
  // accum[0] = sum(diag), accum[1] = sum(lse)
  out[0] = (accum[1] - accum[0]) * (1.0f / (float)NN);
}

extern "C" void kernel_launch(void* const* d_in, const int* in_sizes, int n_in,
                              void* d_out, int out_size, void* d_ws, size_t ws_size,
                              hipStream_t stream) {
  const float* r = (const float*)d_in[0];
  const float* l = (const float*)d_in[1];
  float* out = (float*)d_out;
  char* ws = (char*)d_ws;

  float* accum = (float*)ws;                                   // [0]=diag,[1]=lse
  u16* Rb = (u16*)(ws + 256);
  u16* Lb = (u16*)(ws + 256 + (size_t)NN * DD * 2);
  float* pm = (float*)(ws + 256 + (size_t)NN * DD * 4);
  float* ps = pm + (size_t)NN * CCHUNK;

  hipMemsetAsync(accum, 0, 8, stream);
  cvt_diag<<<NN * DD / 4 / 256, 256, 0, stream>>>(r, l, Rb, Lb, accum);
  gemm_lse<<<dim3(NN / BM, CCHUNK), 256, 0, stream>>>(Rb, Lb, pm, ps);
  lse_merge<<<NN / 256, 256, 0, stream>>>(pm, ps, accum + 1);
  finalize<<<1, 1, 0, stream>>>(accum, out);
}

// Round 3
// 289.616 us; speedup vs baseline: 1.3128x; 1.3128x over previous
//
#include <hip/hip_runtime.h>
#include <stdint.h>

#define NN 8192
#define DD 1024
#define CCHUNK 16         // column chunks (split-LSE): grid = 64 x 16 = 1024 blocks
#define BM 128            // rows per block
#define BN 128            // cols per strip
#define BK 32             // K tile
#define L2E 1.4426950408889634f
#define NCVT (NN * DD / 4 / 256)   // cvt_diag grid = 8192 blocks

typedef short s8v __attribute__((ext_vector_type(8)));   // 8 bf16 = 4 VGPR
typedef float f4v __attribute__((ext_vector_type(4)));   // MFMA C/D
typedef unsigned short u16;

__device__ __forceinline__ void async16(const void* g, void* l) {
  __builtin_amdgcn_global_load_lds(
      (const __attribute__((address_space(1))) void*)g,
      (__attribute__((address_space(3))) void*)l, 16, 0, 0);
}

__device__ __forceinline__ u16 f2bf(float f) {
  unsigned u = __float_as_uint(f);
  u += 0x7fffu + ((u >> 16) & 1u);   // RNE
  return (u16)(u >> 16);
}

// ---- fp32 -> bf16 conversion fused with exact fp32 diagonal partials ----
// Per-block partial sum written to pdiag[block] — NO same-address atomics
// (8192 contended atomicAdds cost ~100 µs in R2).
__global__ void cvt_diag(const float* __restrict__ r, const float* __restrict__ l,
                         u16* __restrict__ rb, u16* __restrict__ lb,
                         float* __restrict__ pdiag) {
  int tid = threadIdx.x, lane = tid & 63, w = tid >> 6;
  size_t i = (size_t)blockIdx.x * blockDim.x + tid;  // float4 index
  float4 a = ((const float4*)r)[i];
  float4 b = ((const float4*)l)[i];
  ushort4 oa, ob;
  oa.x = f2bf(a.x); oa.y = f2bf(a.y); oa.z = f2bf(a.z); oa.w = f2bf(a.w);
  ob.x = f2bf(b.x); ob.y = f2bf(b.y); ob.z = f2bf(b.z); ob.w = f2bf(b.w);
  ((ushort4*)rb)[i] = oa;
  ((ushort4*)lb)[i] = ob;
  float s = a.x * b.x + a.y * b.y + a.z * b.z + a.w * b.w;
#pragma unroll
  for (int m = 1; m <= 32; m <<= 1) s += __shfl_xor(s, m);
  __shared__ float red[4];
  if (lane == 0) red[w] = s;
  __syncthreads();
  if (tid == 0) pdiag[blockIdx.x] = red[0] + red[1] + red[2] + red[3];
}

// ---- fused bf16 GEMM + online logsumexp over one column chunk ----
// LDS layout is XOR-swizzled: physical granule slot (g&3) holds logical
// k-quad (g&3) ^ ((row>>1)&3). Applied on the staging-fetch side (which
// global granule each lane pulls) since global_load_lds placement is
// lane-ordered; mirrored in the fragment-read index. Breaks the 8-way
// bank conflict of the 64 B row stride (bank group was (row&1)*16+quad*4).
__global__ __launch_bounds__(256, 2) void gemm_lse(
    const u16* __restrict__ Rb, const u16* __restrict__ Lb,
    float* __restrict__ pm, float* __restrict__ ps) {
  __shared__ u16 As[BM * BK];          // 8 KB
  __shared__ u16 Bs[BN * BK];          // 8 KB
  __shared__ float smm[2][BM], sms[2][BM];

  const int tid = threadIdx.x, lane = tid & 63, w = tid >> 6;
  const int wy = w >> 1, wx = w & 1;
  const int quad = lane >> 4, l15 = lane & 15;
  const int row0 = blockIdx.x * BM;
  const int col0 = blockIdx.y * (NN / CCHUNK);

  // staging: physical granule g = (w*2+c)*64 + lane; row = g>>2;
  // fetch logical kq = (g&3) ^ ((row>>1)&3)
  size_t gAo[2], gBo[2];
  u16 *lAp[2], *lBp[2];
#pragma unroll
  for (int c = 0; c < 2; ++c) {
    int g = (w * 2 + c) * 64 + lane;
    int row = g >> 2;
    int kq = (g & 3) ^ ((row >> 1) & 3);
    gAo[c] = (size_t)(row0 + row) * DD + kq * 8;
    gBo[c] = (size_t)row * DD + kq * 8;   // + strip col base later
    lAp[c] = As + (w * 2 + c) * 512;      // wave-uniform LDS base
    lBp[c] = Bs + (w * 2 + c) * 512;
  }

  const int sw = (l15 >> 1) & 3;          // read-side swizzle

  float m_run[4][4], s_run[4][4];
#pragma unroll
  for (int i = 0; i < 4; ++i)
#pragma unroll
    for (int j = 0; j < 4; ++j) { m_run[i][j] = -__builtin_inff(); s_run[i][j] = 0.f; }

  for (int strip = 0; strip < (NN / CCHUNK) / BN; ++strip) {
    const u16* gB_base = Lb + (size_t)(col0 + strip * BN) * DD;
    f4v acc[4][4];
#pragma unroll
    for (int ri = 0; ri < 4; ++ri)
#pragma unroll
      for (int ci = 0; ci < 4; ++ci) acc[ri][ci] = (f4v){0.f, 0.f, 0.f, 0.f};

    for (int kt = 0; kt < DD / BK; ++kt) {
      const int k = kt * BK;
      async16(Rb + gAo[0] + k, lAp[0]);
      async16(Rb + gAo[1] + k, lAp[1]);
      async16(gB_base + gBo[0] + k, lBp[0]);
      async16(gB_base + gBo[1] + k, lBp[1]);
      __syncthreads();
      s8v a[4], b[4];
#pragma unroll
      for (int ri = 0; ri < 4; ++ri)
        a[ri] = *(const s8v*)(As + (wy * 64 + ri * 16 + l15) * BK + ((quad ^ sw) * 8));
#pragma unroll
      for (int ci = 0; ci < 4; ++ci)
        b[ci] = *(const s8v*)(Bs + (wx * 64 + ci * 16 + l15) * BK + ((quad ^ sw) * 8));
#pragma unroll
      for (int ri = 0; ri < 4; ++ri)
#pragma unroll
        for (int ci = 0; ci < 4; ++ci)
          acc[ri][ci] = __builtin_amdgcn_mfma_f32_16x16x32_bf16(a[ri], b[ci], acc[ri][ci], 0, 0, 0);
      __syncthreads();
    }

    // per-thread online update, pure VALU (cross-lane merge deferred to end)
#pragma unroll
    for (int ri = 0; ri < 4; ++ri) {
#pragma unroll
      for (int reg = 0; reg < 4; ++reg) {
        float v0 = acc[ri][0][reg], v1 = acc[ri][1][reg];
        float v2 = acc[ri][2][reg], v3 = acc[ri][3][reg];
        float t = fmaxf(fmaxf(v0, v1), fmaxf(v2, v3));
        float mo = m_run[ri][reg];
        float mn = fmaxf(mo, t);
        float c = mn * L2E;
        float p = exp2f(fmaf(v0, L2E, -c)) + exp2f(fmaf(v1, L2E, -c)) +
                  exp2f(fmaf(v2, L2E, -c)) + exp2f(fmaf(v3, L2E, -c));
        s_run[ri][reg] = fmaf(s_run[ri][reg], exp2f(fmaf(mo, L2E, -c)), p);
        m_run[ri][reg] = mn;
      }
    }
  }

  // ---- end-of-kernel merge ----
#pragma unroll
  for (int ri = 0; ri < 4; ++ri) {
#pragma unroll
    for (int reg = 0; reg < 4; ++reg) {
      float m = m_run[ri][reg], s = s_run[ri][reg];
#pragma unroll
      for (int msk = 1; msk <= 8; msk <<= 1) {
        float om = __shfl_xor(m, msk);
        float os = __shfl_xor(s, msk);
        float M = fmaxf(m, om);
        s = s * exp2f((m - M) * L2E) + os * exp2f((om - M) * L2E);
        m = M;
      }
      m_run[ri][reg] = m; s_run[ri][reg] = s;
    }
  }
  __syncthreads();
  if (l15 == 0) {
#pragma unroll
    for (int ri = 0; ri < 4; ++ri)
#pragma unroll
      for (int reg = 0; reg < 4; ++reg) {
        int r = wy * 64 + ri * 16 + quad * 4 + reg;
        smm[wx][r] = m_run[ri][reg];
        sms[wx][r] = s_run[ri][reg];
      }
  }
  __syncthreads();
  if (tid < BM) {
    float m1 = smm[0][tid], m2 = smm[1][tid];
    float M = fmaxf(m1, m2);
    float S = sms[0][tid] * exp2f((m1 - M) * L2E) + sms[1][tid] * exp2f((m2 - M) * L2E);
    pm[(size_t)(row0 + tid) * CCHUNK + blockIdx.y] = M;
    ps[(size_t)(row0 + tid) * CCHUNK + blockIdx.y] = S;
  }
}

// ---- combine chunk partials -> lse per row -> sum (32 atomics total, fine) ----
__global__ void lse_merge(const float* __restrict__ pm, const float* __restrict__ ps,
                          float* __restrict__ accum) {
  int tid = threadIdx.x, lane = tid & 63, w = tid >> 6;
  int row = blockIdx.x * 256 + tid;
  float M = -__builtin_inff();
#pragma unroll
  for (int c = 0; c < CCHUNK; ++c) M = fmaxf(M, pm[(size_t)row * CCHUNK + c]);
  float S = 0.f;
#pragma unroll
  for (int c = 0; c < CCHUNK; ++c)
    S += ps[(size_t)row * CCHUNK + c] * exp2f((pm[(size_t)row * CCHUNK + c] - M) * L2E);
  float lse = M + logf(S);
#pragma unroll
  for (int m = 1; m <= 32; m <<= 1) lse += __shfl_xor(lse, m);
  __shared__ float red[4];
  if (lane == 0) red[w] = lse;
  __syncthreads();
  if (tid == 0) atomicAdd(accum, red[0] + red[1] + red[2] + red[3]);
}

// ---- reduce diag partials + combine ----
__global__ void finalize(const float* __restrict__ accum,
                         const float* __restrict__ pdiag,
                         float* __restrict__ out) {
  int tid = threadIdx.x, lane = tid & 63, w = tid >> 6;
  float s = 0.f;
  for (int i = tid; i < NCVT; i += 256) s += pdiag[i];
#pragma unroll
  for (int m = 1; m <= 32; m <<= 1) s += __shfl_xor(s, m);
  __shared__ float red[4];
  if (lane == 0) red[w] = s;
  __syncthreads();
  if (tid == 0) {
    float diag = red[0] + red[1] + red[2] + red[3];
    out[0] = (accum[0] - diag) * (1.0f / (float)NN);
  }
}

extern "C" void kernel_launch(void* const* d_in, const int* in_sizes, int n_in,
                              void* d_out, int out_size, void* d_ws, size_t ws_size,
                              hipStream_t stream) {
  const float* r = (const float*)d_in[0];
  const float* l = (const float*)d_in[1];
  float* out = (float*)d_out;
  char* ws = (char*)d_ws;

  float* accum = (float*)ws;                                   // [0] = lse sum
  u16* Rb = (u16*)(ws + 256);
  u16* Lb = (u16*)(ws + 256 + (size_t)NN * DD * 2);
  float* pm = (float*)(ws + 256 + (size_t)NN * DD * 4);
  float* ps = pm + (size_t)NN * CCHUNK;
  float* pdiag = ps + (size_t)NN * CCHUNK;

  hipMemsetAsync(accum, 0, 4, stream);
  cvt_diag<<<NCVT, 256, 0, stream>>>(r, l, Rb, Lb, pdiag);
  gemm_lse<<<dim3(NN / BM, CCHUNK), 256, 0, stream>>>(Rb, Lb, pm, ps);
  lse_merge<<<NN / 256, 256, 0, stream>>>(pm, ps, accum);
  finalize<<<1, 256, 0, stream>>>(accum, pdiag, out);
}

// Round 4
// 267.168 us; speedup vs baseline: 1.4231x; 1.0840x over previous
//
#include <hip/hip_runtime.h>
#include <stdint.h>

#define NN 8192
#define DD 1024
#define NCH 24            // column chunks; grid = 64 x 24 = 1536 = flat rounds at 2 OR 3 blocks/CU
#define BM 128            // rows per block
#define BN 128            // cols per strip
#define BK 64             // K tile (32 MFMA per barrier pair)
#define L2E 1.4426950408889634f
#define NCVT (NN * DD / 4 / 256)   // cvt_diag grid = 8192 blocks

typedef short s8v __attribute__((ext_vector_type(8)));   // 8 bf16 = 4 VGPR
typedef float f4v __attribute__((ext_vector_type(4)));   // MFMA C/D
typedef unsigned short u16;

__device__ __forceinline__ void async16(const void* g, void* l) {
  __builtin_amdgcn_global_load_lds(
      (const __attribute__((address_space(1))) void*)g,
      (__attribute__((address_space(3))) void*)l, 16, 0, 0);
}

__device__ __forceinline__ u16 f2bf(float f) {
  unsigned u = __float_as_uint(f);
  u += 0x7fffu + ((u >> 16) & 1u);   // RNE
  return (u16)(u >> 16);
}

// ---- fp32 -> bf16 conversion fused with exact fp32 diagonal partials ----
__global__ void cvt_diag(const float* __restrict__ r, const float* __restrict__ l,
                         u16* __restrict__ rb, u16* __restrict__ lb,
                         float* __restrict__ pdiag) {
  int tid = threadIdx.x, lane = tid & 63, w = tid >> 6;
  size_t i = (size_t)blockIdx.x * blockDim.x + tid;  // float4 index
  float4 a = ((const float4*)r)[i];
  float4 b = ((const float4*)l)[i];
  ushort4 oa, ob;
  oa.x = f2bf(a.x); oa.y = f2bf(a.y); oa.z = f2bf(a.z); oa.w = f2bf(a.w);
  ob.x = f2bf(b.x); ob.y = f2bf(b.y); ob.z = f2bf(b.z); ob.w = f2bf(b.w);
  ((ushort4*)rb)[i] = oa;
  ((ushort4*)lb)[i] = ob;
  float s = a.x * b.x + a.y * b.y + a.z * b.z + a.w * b.w;
#pragma unroll
  for (int m = 1; m <= 32; m <<= 1) s += __shfl_xor(s, m);
  __shared__ float red[4];
  if (lane == 0) red[w] = s;
  __syncthreads();
  if (tid == 0) pdiag[blockIdx.x] = red[0] + red[1] + red[2] + red[3];
}

// ---- fused bf16 GEMM + online logsumexp ----
// LDS layout [row][slot] with 8 slots of 16B per row (BK=64 -> 128 B rows);
// XOR swizzle slot_phys = slot_logical ^ (row & 7) keeps fragment reads at
// 2 lanes/bank-group (free). Swizzle applied on the staging-fetch side
// (global_load_lds placement is lane-ordered) and mirrored at read.
__global__ __launch_bounds__(256, 3) void gemm_lse(
    const u16* __restrict__ Rb, const u16* __restrict__ Lb,
    float* __restrict__ pm, float* __restrict__ ps) {
  __shared__ u16 As[BM * BK];          // 16 KB
  __shared__ u16 Bs[BN * BK];          // 16 KB
  __shared__ float smm[2][BM], sms[2][BM];

  const int tid = threadIdx.x, lane = tid & 63, w = tid >> 6;
  const int wy = w >> 1, wx = w & 1;
  const int quad = lane >> 4, l15 = lane & 15;
  const int rb = blockIdx.x & 63, ch = blockIdx.x >> 6;   // consecutive blocks share ch -> L2 reuse of B
  const int row0 = rb * BM;
  const int s0 = (ch * 64) / NCH, s1 = ((ch + 1) * 64) / NCH;  // 2-3 strips per chunk

  // staging: thread handles physical granules p = (c*4+w)*64 + lane, c=0..3
  // (per matrix). p -> row = p>>3, phys slot = p&7, fetch logical kq = slot^(row&7).
  int gAo[4], gBo[4];
  u16 *lAp[4], *lBp[4];
#pragma unroll
  for (int c = 0; c < 4; ++c) {
    int p = (c * 4 + w) * 64 + lane;
    int row = p >> 3;
    int kq = (p & 7) ^ (row & 7);
    gAo[c] = (row0 + row) * DD + kq * 8;
    gBo[c] = row * DD + kq * 8;              // + strip col base later
    lAp[c] = As + (c * 4 + w) * 512;         // wave-uniform LDS base (1 KB per call)
    lBp[c] = Bs + (c * 4 + w) * 512;
  }

  // fragment-read bases (u16 elems). Logical granule for (half,quad) sits at
  // physical slot (half*4+quad)^(l15&7); elem offset = that*8 = th0 ^ (half*32).
  const int baseA = (wy * 64 + l15) * BK;
  const int baseB = (wx * 64 + l15) * BK;
  const int th0 = (quad ^ (l15 & 7)) * 8;
  const int th1 = th0 ^ 32;

  float m_run[4][4], s_run[4][4];
#pragma unroll
  for (int i = 0; i < 4; ++i)
#pragma unroll
    for (int j = 0; j < 4; ++j) { m_run[i][j] = -__builtin_inff(); s_run[i][j] = 0.f; }

  for (int strip = s0; strip < s1; ++strip) {
    const u16* gB = Lb + (size_t)strip * BN * DD;
    f4v acc[4][4];
#pragma unroll
    for (int ri = 0; ri < 4; ++ri)
#pragma unroll
      for (int ci = 0; ci < 4; ++ci) acc[ri][ci] = (f4v){0.f, 0.f, 0.f, 0.f};

    for (int kt = 0; kt < DD / BK; ++kt) {
      const int k = kt * BK;
#pragma unroll
      for (int c = 0; c < 4; ++c) async16(Rb + gAo[c] + k, lAp[c]);
#pragma unroll
      for (int c = 0; c < 4; ++c) async16(gB + gBo[c] + k, lBp[c]);
      __syncthreads();
#pragma unroll
      for (int half = 0; half < 2; ++half) {
        const int th = half ? th1 : th0;
        s8v a[4], b[4];
#pragma unroll
        for (int ri = 0; ri < 4; ++ri)
          a[ri] = *(const s8v*)(As + baseA + ri * 16 * BK + th);
#pragma unroll
        for (int ci = 0; ci < 4; ++ci)
          b[ci] = *(const s8v*)(Bs + baseB + ci * 16 * BK + th);
#pragma unroll
        for (int ri = 0; ri < 4; ++ri)
#pragma unroll
          for (int ci = 0; ci < 4; ++ci)
            acc[ri][ci] = __builtin_amdgcn_mfma_f32_16x16x32_bf16(a[ri], b[ci], acc[ri][ci], 0, 0, 0);
      }
      __syncthreads();
    }

    // per-thread online update, pure VALU
#pragma unroll
    for (int ri = 0; ri < 4; ++ri) {
#pragma unroll
      for (int reg = 0; reg < 4; ++reg) {
        float v0 = acc[ri][0][reg], v1 = acc[ri][1][reg];
        float v2 = acc[ri][2][reg], v3 = acc[ri][3][reg];
        float t = fmaxf(fmaxf(v0, v1), fmaxf(v2, v3));
        float mo = m_run[ri][reg];
        float mn = fmaxf(mo, t);
        float c = mn * L2E;
        float p = exp2f(fmaf(v0, L2E, -c)) + exp2f(fmaf(v1, L2E, -c)) +
                  exp2f(fmaf(v2, L2E, -c)) + exp2f(fmaf(v3, L2E, -c));
        s_run[ri][reg] = fmaf(s_run[ri][reg], exp2f(fmaf(mo, L2E, -c)), p);
        m_run[ri][reg] = mn;
      }
    }
  }

  // ---- end-of-kernel merge ----
#pragma unroll
  for (int ri = 0; ri < 4; ++ri) {
#pragma unroll
    for (int reg = 0; reg < 4; ++reg) {
      float m = m_run[ri][reg], s = s_run[ri][reg];
#pragma unroll
      for (int msk = 1; msk <= 8; msk <<= 1) {
        float om = __shfl_xor(m, msk);
        float os = __shfl_xor(s, msk);
        float M = fmaxf(m, om);
        s = s * exp2f((m - M) * L2E) + os * exp2f((om - M) * L2E);
        m = M;
      }
      m_run[ri][reg] = m; s_run[ri][reg] = s;
    }
  }
  __syncthreads();
  if (l15 == 0) {
#pragma unroll
    for (int ri = 0; ri < 4; ++ri)
#pragma unroll
      for (int reg = 0; reg < 4; ++reg) {
        int r = wy * 64 + ri * 16 + quad * 4 + reg;
        smm[wx][r] = m_run[ri][reg];
        sms[wx][r] = s_run[ri][reg];
      }
  }
  __syncthreads();
  if (tid < BM) {
    float m1 = smm[0][tid], m2 = smm[1][tid];
    float M = fmaxf(m1, m2);
    float S = sms[0][tid] * exp2f((m1 - M) * L2E) + sms[1][tid] * exp2f((m2 - M) * L2E);
    // transposed layout [chunk][row] -> coalesced reads in lse_merge
    pm[(size_t)ch * NN + row0 + tid] = M;
    ps[(size_t)ch * NN + row0 + tid] = S;
  }
}

// ---- combine chunk partials -> lse per row -> sum ----
__global__ void lse_merge(const float* __restrict__ pm, const float* __restrict__ ps,
                          float* __restrict__ accum) {
  int tid = threadIdx.x, lane = tid & 63, w = tid >> 6;
  int row = blockIdx.x * 256 + tid;
  float M = -__builtin_inff();
#pragma unroll
  for (int c = 0; c < NCH; ++c) M = fmaxf(M, pm[(size_t)c * NN + row]);
  float S = 0.f;
#pragma unroll
  for (int c = 0; c < NCH; ++c)
    S += ps[(size_t)c * NN + row] * exp2f((pm[(size_t)c * NN + row] - M) * L2E);
  float lse = M + logf(S);
#pragma unroll
  for (int m = 1; m <= 32; m <<= 1) lse += __shfl_xor(lse, m);
  __shared__ float red[4];
  if (lane == 0) red[w] = lse;
  __syncthreads();
  if (tid == 0) atomicAdd(accum, red[0] + red[1] + red[2] + red[3]);
}

// ---- reduce diag partials + combine ----
__global__ void finalize(const float* __restrict__ accum,
                         const float* __restrict__ pdiag,
                         float* __restrict__ out) {
  int tid = threadIdx.x, lane = tid & 63, w = tid >> 6;
  float s = 0.f;
  for (int i = tid; i < NCVT; i += 256) s += pdiag[i];
#pragma unroll
  for (int m = 1; m <= 32; m <<= 1) s += __shfl_xor(s, m);
  __shared__ float red[4];
  if (lane == 0) red[w] = s;
  __syncthreads();
  if (tid == 0) {
    float diag = red[0] + red[1] + red[2] + red[3];
    out[0] = (accum[0] - diag) * (1.0f / (float)NN);
  }
}

extern "C" void kernel_launch(void* const* d_in, const int* in_sizes, int n_in,
                              void* d_out, int out_size, void* d_ws, size_t ws_size,
                              hipStream_t stream) {
  const float* r = (const float*)d_in[0];
  const float* l = (const float*)d_in[1];
  float* out = (float*)d_out;
  char* ws = (char*)d_ws;

  float* accum = (float*)ws;                                   // [0] = lse sum
  u16* Rb = (u16*)(ws + 256);
  u16* Lb = (u16*)(ws + 256 + (size_t)NN * DD * 2);
  float* pm = (float*)(ws + 256 + (size_t)NN * DD * 4);
  float* ps = pm + (size_t)NN * NCH;
  float* pdiag = ps + (size_t)NN * NCH;

  hipMemsetAsync(accum, 0, 4, stream);
  cvt_diag<<<NCVT, 256, 0, stream>>>(r, l, Rb, Lb, pdiag);
  gemm_lse<<<dim3(64 * NCH), 256, 0, stream>>>(Rb, Lb, pm, ps);
  lse_merge<<<NN / 256, 256, 0, stream>>>(pm, ps, accum);
  finalize<<<1, 256, 0, stream>>>(accum, pdiag, out);
}